// Round 10
// baseline (1188.453 us; speedup 1.0000x reference)
//
#include <hip/hip_runtime.h>
#include <math.h>

// GCN forward: N=100000, IN_DIM=128, D=64, L=4, C=40, E=1.6M.
// Round 10: fuse agg into gemm_stats (gather -> sA LDS tile directly; agg
// buffer never materialized: saves 25MB write + 25MB read per layer), and
// restructure the gather to 2-edges-per-load: lane l<32 = even edge rows,
// l>=32 = odd rows, each lane loads uint = 2 bf16 features; even/odd combined
// with one shfl_xor(32). Round-9 counters: agg 4x90us dominated (FETCH 88MB,
// 1.28TB/s, VALUBusy 18%). Everything else unchanged.

#define LEAKY_SLOPE 0.2f
#define BN_EPS 1e-5f
#define DEG_CAP 48

__device__ __forceinline__ unsigned short f2bf(float f) {
  unsigned int x = __float_as_uint(f);
  unsigned int r = (x + 0x7FFFu + ((x >> 16) & 1u)) >> 16;  // RNE
  return (unsigned short)r;
}

// ---------------- XCD-windowed degree histogram (src) ----------------
__global__ __launch_bounds__(256, 8)
void hist_kernel(const int* __restrict__ src, int* __restrict__ cnt_src, int E, int N) {
  int bid = blockIdx.x;
  int w = bid & 7;                         // XCD id (round-robin dispatch)
  int chunk = (N + 7) >> 3;
  int lo = w * chunk;
  int hi = min(lo + chunk, N);
  int i = (bid >> 3) * blockDim.x + threadIdx.x;
  int stride = (gridDim.x >> 3) * blockDim.x;
  for (; i < E; i += stride) {
    int s = src[i];
    if (s >= lo && s < hi) atomicAdd(&cnt_src[s], 1);
  }
}

// ---------------- XCD-windowed padded fill: bucket[d][pos] = src ----------------
__global__ __launch_bounds__(256, 8)
void fill_kernel(const int* __restrict__ src, const int* __restrict__ dst,
                 int* __restrict__ cnt_dst, int* __restrict__ bucket, int E, int N) {
  int bid = blockIdx.x;
  int w = bid & 7;                         // XCD id; bucket window 2.4MB < 4MiB L2
  int chunk = (N + 7) >> 3;
  int lo = w * chunk;
  int hi = min(lo + chunk, N);
  int i = (bid >> 3) * blockDim.x + threadIdx.x;
  int stride = (gridDim.x >> 3) * blockDim.x;
  for (; i < E; i += stride) {
    int d = dst[i];
    if (d >= lo && d < hi) {
      int pos = atomicAdd(&cnt_dst[d], 1);
      if (pos < DEG_CAP) bucket[d * DEG_CAP + pos] = src[i];
    }
  }
}

// ---------------- norms from degree counts ----------------
__global__ __launch_bounds__(256, 8)
void norms_kernel(const int* __restrict__ cnt_src, const int* __restrict__ cnt_dst,
                  float* __restrict__ norm_src, float* __restrict__ norm_dst, int N) {
  int i = blockIdx.x * blockDim.x + threadIdx.x;
  if (i < N) {
    norm_src[i] = rsqrtf(fmaxf((float)cnt_src[i], 1.0f));
    norm_dst[i] = rsqrtf(fmaxf((float)cnt_dst[i], 1.0f));
  }
}

// ---------------- input GEMM: h = V @ W_in + b_in (128->64); hs = bf16(h*norm_src) ----
__global__ __launch_bounds__(256) __attribute__((amdgpu_waves_per_eu(3, 4)))
void input_gemm_kernel(const float* __restrict__ V, const float* __restrict__ W_in,
                       const float* __restrict__ b_in, const float* __restrict__ norm_src,
                       float* __restrict__ h, unsigned short* __restrict__ hs, int N) {
  __shared__ __align__(16) float sW[128][64];
  __shared__ __align__(16) float sA[32][132];
  int tid = threadIdx.x;
  int c0 = (tid & 15) * 4;
  int rp = tid >> 4;
  int base = blockIdx.x * 32;

  float4 b4 = *(const float4*)&b_in[c0];

  #pragma unroll
  for (int it = 0; it < 8; it++) {
    int i = tid + it * 256;
    int r = i >> 4, cc = (i & 15) * 4;
    *(float4*)&sW[r][cc] = *(const float4*)&W_in[r * 64 + cc];
  }
  #pragma unroll
  for (int it = 0; it < 4; it++) {
    int i = tid + it * 256;
    int r = i >> 5, cc = (i & 31) * 4;
    int n = base + r;
    float4 v = make_float4(0.f, 0.f, 0.f, 0.f);
    if (n < N) v = *(const float4*)&V[(size_t)n * 128 + cc];
    *(float4*)&sA[r][cc] = v;
  }
  __syncthreads();

  int r0 = rp * 2, r1 = rp * 2 + 1;
  float acc0[4] = {0.f, 0.f, 0.f, 0.f};
  float acc1[4] = {0.f, 0.f, 0.f, 0.f};
  #pragma unroll 4
  for (int d0 = 0; d0 < 128; d0 += 4) {
    float4 wr0 = *(const float4*)&sW[d0 + 0][c0];
    float4 wr1 = *(const float4*)&sW[d0 + 1][c0];
    float4 wr2 = *(const float4*)&sW[d0 + 2][c0];
    float4 wr3 = *(const float4*)&sW[d0 + 3][c0];
    float4 a0 = *(const float4*)&sA[r0][d0];
    float4 a1 = *(const float4*)&sA[r1][d0];
    acc0[0] += a0.x * wr0.x + a0.y * wr1.x + a0.z * wr2.x + a0.w * wr3.x;
    acc0[1] += a0.x * wr0.y + a0.y * wr1.y + a0.z * wr2.y + a0.w * wr3.y;
    acc0[2] += a0.x * wr0.z + a0.y * wr1.z + a0.z * wr2.z + a0.w * wr3.z;
    acc0[3] += a0.x * wr0.w + a0.y * wr1.w + a0.z * wr2.w + a0.w * wr3.w;
    acc1[0] += a1.x * wr0.x + a1.y * wr1.x + a1.z * wr2.x + a1.w * wr3.x;
    acc1[1] += a1.x * wr0.y + a1.y * wr1.y + a1.z * wr2.y + a1.w * wr3.y;
    acc1[2] += a1.x * wr0.z + a1.y * wr1.z + a1.z * wr2.z + a1.w * wr3.z;
    acc1[3] += a1.x * wr0.w + a1.y * wr1.w + a1.z * wr2.w + a1.w * wr3.w;
  }

  int n0 = base + r0, n1 = base + r1;
  if (n0 < N) {
    float4 o = make_float4(acc0[0] + b4.x, acc0[1] + b4.y, acc0[2] + b4.z, acc0[3] + b4.w);
    *(float4*)&h[(size_t)n0 * 64 + c0] = o;
    float ns = norm_src[n0];
    ushort4 s = make_ushort4(f2bf(o.x * ns), f2bf(o.y * ns), f2bf(o.z * ns), f2bf(o.w * ns));
    *(ushort4*)&hs[(size_t)n0 * 64 + c0] = s;
  }
  if (n1 < N) {
    float4 o = make_float4(acc1[0] + b4.x, acc1[1] + b4.y, acc1[2] + b4.z, acc1[3] + b4.w);
    *(float4*)&h[(size_t)n1 * 64 + c0] = o;
    float ns = norm_src[n1];
    ushort4 s = make_ushort4(f2bf(o.x * ns), f2bf(o.y * ns), f2bf(o.z * ns), f2bf(o.w * ns));
    *(ushort4*)&hs[(size_t)n1 * 64 + c0] = s;
  }
}

// ---------------- fused agg + layer GEMM + BN stats ----------------
// Gather phase: wave per node (16 nodes/wave sequential), lane l<32 = even
// edge rows, l>=32 = odd rows; each lane loads uint = 2 bf16 features of its
// row; even/odd partials combined via shfl_xor(32). Result scaled by norm_dst
// lands directly in sA (the GEMM A-tile). Then GEMM + stats as before.
__global__ __launch_bounds__(256) __attribute__((amdgpu_waves_per_eu(4, 4)))
void agg_gemm_stats_kernel(const unsigned short* __restrict__ hs,
                           const float* __restrict__ norm_dst,
                           const int* __restrict__ cnt_dst,
                           const int* __restrict__ bucket,
                           const float* __restrict__ W, const float* __restrict__ b,
                           float* __restrict__ hc, float* __restrict__ stats, int N) {
  __shared__ __align__(16) float sW[64][64];
  __shared__ __align__(16) float sA[64][68];
  int tid = threadIdx.x;
  int lane = tid & 63;
  int wv = tid >> 6;
  int half = lane >> 5;          // 0: even edge rows, 1: odd
  int l = lane & 31;             // feature pair: 2l, 2l+1
  int base = blockIdx.x * 64;

  // stage W
  #pragma unroll
  for (int it = 0; it < 4; it++) {
    int i = tid + it * 256;
    int r = i >> 4, c4 = (i & 15) * 4;
    *(float4*)&sW[r][c4] = *(const float4*)&W[r * 64 + c4];
  }

  // gather phase: wave wv owns tile rows wv*16 .. wv*16+15
  for (int i = 0; i < 16; i++) {
    int r = wv * 16 + i;
    int n = base + r;            // wave-uniform
    float acc0 = 0.f, acc1 = 0.f;
    if (n < N) {
      int len = min(cnt_dst[n], DEG_CAP);
      const int* bkt = bucket + (size_t)n * DEG_CAP;
      for (int j = 0; j < len; j += 16) {
        #pragma unroll
        for (int k = 0; k < 8; k++) {
          int e = j + 2 * k + half;
          if (e < len) {
            int sidx = bkt[e];
            unsigned int u = *(const unsigned int*)&hs[(size_t)sidx * 64 + 2 * l];
            acc0 += __uint_as_float(u << 16);
            acc1 += __uint_as_float(u & 0xFFFF0000u);
          }
        }
      }
      acc0 += __shfl_xor(acc0, 32);   // combine even/odd halves
      acc1 += __shfl_xor(acc1, 32);
      float nd = norm_dst[n];
      acc0 *= nd; acc1 *= nd;
    }
    if (half == 0) {
      sA[r][2 * l]     = acc0;
      sA[r][2 * l + 1] = acc1;
    }
  }
  __syncthreads();

  // GEMM + stats (identical to round-9 gemm_stats)
  int cg = lane & 15;
  int ng = lane >> 4;
  int nrow0 = wv * 16 + ng * 4;

  float4 b4 = *(const float4*)&b[cg * 4];

  float acc[4][4];
  #pragma unroll
  for (int i = 0; i < 4; i++)
    #pragma unroll
    for (int c = 0; c < 4; c++) acc[i][c] = 0.f;

  #pragma unroll 4
  for (int d0 = 0; d0 < 64; d0 += 4) {
    float4 wr0 = *(const float4*)&sW[d0 + 0][cg * 4];
    float4 wr1 = *(const float4*)&sW[d0 + 1][cg * 4];
    float4 wr2 = *(const float4*)&sW[d0 + 2][cg * 4];
    float4 wr3 = *(const float4*)&sW[d0 + 3][cg * 4];
    #pragma unroll
    for (int i = 0; i < 4; i++) {
      float4 av = *(const float4*)&sA[nrow0 + i][d0];
      acc[i][0] += av.x * wr0.x + av.y * wr1.x + av.z * wr2.x + av.w * wr3.x;
      acc[i][1] += av.x * wr0.y + av.y * wr1.y + av.z * wr2.y + av.w * wr3.y;
      acc[i][2] += av.x * wr0.z + av.y * wr1.z + av.z * wr2.z + av.w * wr3.z;
      acc[i][3] += av.x * wr0.w + av.y * wr1.w + av.z * wr2.w + av.w * wr3.w;
    }
  }

  float st_s0=0.f,st_s1=0.f,st_s2=0.f,st_s3=0.f;
  float st_q0=0.f,st_q1=0.f,st_q2=0.f,st_q3=0.f;
  #pragma unroll
  for (int i = 0; i < 4; i++) {
    int n = base + nrow0 + i;
    if (n < N) {
      float4 o;
      o.x = acc[i][0] + b4.x; o.y = acc[i][1] + b4.y;
      o.z = acc[i][2] + b4.z; o.w = acc[i][3] + b4.w;
      *(float4*)&hc[(size_t)n * 64 + cg * 4] = o;
      st_s0 += o.x; st_s1 += o.y; st_s2 += o.z; st_s3 += o.w;
      st_q0 += o.x * o.x; st_q1 += o.y * o.y;
      st_q2 += o.z * o.z; st_q3 += o.w * o.w;
    }
  }

  __syncthreads();
  int rr = wv * 4 + ng;
  *(float4*)&sA[rr][cg * 4]      = make_float4(st_s0, st_s1, st_s2, st_s3);
  *(float4*)&sA[16 + rr][cg * 4] = make_float4(st_q0, st_q1, st_q2, st_q3);
  __syncthreads();
  if (tid < 64) {
    float s = 0.f, q = 0.f;
    #pragma unroll
    for (int r = 0; r < 16; r++) { s += sA[r][tid]; q += sA[16 + r][tid]; }
    atomicAdd(&stats[tid], s);
    atomicAdd(&stats[64 + tid], q);
  }
}

// ---------------- fused BN finalize + apply + residual + bf16 pre-scale ----------------
__global__ __launch_bounds__(256, 8)
void apply_kernel(const float* __restrict__ hc, const float* __restrict__ stats,
                  const float* __restrict__ gamma, const float* __restrict__ beta,
                  const float* __restrict__ norm_src, float* __restrict__ h,
                  unsigned short* __restrict__ hs, int N, int write_hs) {
  __shared__ float s_scale[64];
  __shared__ float s_shift[64];
  int tid = threadIdx.x;
  if (tid < 64) {
    float s = stats[tid];
    float ss = stats[64 + tid];
    float invN = 1.0f / (float)N;
    float mean = s * invN;
    float var = fmaxf(ss * invN - mean * mean, 0.0f);
    float scale = gamma[tid] * rsqrtf(var + BN_EPS);
    s_scale[tid] = scale;
    s_shift[tid] = beta[tid] - mean * scale;
  }
  __syncthreads();
  int total4 = N * 16;
  int i = blockIdx.x * blockDim.x + threadIdx.x;
  int stride = gridDim.x * blockDim.x;
  for (; i < total4; i += stride) {
    float4 v = ((const float4*)hc)[i];
    float4 r = ((const float4*)h)[i];
    int cb = (i * 4) & 63;
    int n = i >> 4;
    float o0 = v.x * s_scale[cb + 0] + s_shift[cb + 0];
    float o1 = v.y * s_scale[cb + 1] + s_shift[cb + 1];
    float o2 = v.z * s_scale[cb + 2] + s_shift[cb + 2];
    float o3 = v.w * s_scale[cb + 3] + s_shift[cb + 3];
    o0 = (o0 >= 0.f) ? o0 : LEAKY_SLOPE * o0;
    o1 = (o1 >= 0.f) ? o1 : LEAKY_SLOPE * o1;
    o2 = (o2 >= 0.f) ? o2 : LEAKY_SLOPE * o2;
    o3 = (o3 >= 0.f) ? o3 : LEAKY_SLOPE * o3;
    float4 oh;
    oh.x = o0 + r.x; oh.y = o1 + r.y; oh.z = o2 + r.z; oh.w = o3 + r.w;
    ((float4*)h)[i] = oh;
    if (write_hs) {
      float nsc = norm_src[n];
      ushort4 os = make_ushort4(f2bf(oh.x * nsc), f2bf(oh.y * nsc),
                                f2bf(oh.z * nsc), f2bf(oh.w * nsc));
      ((ushort4*)hs)[i] = os;
    }
  }
}

// ---------------- output: logits = h @ W_out + b_out; log_softmax ----------------
__global__ __launch_bounds__(256, 4)
void out_kernel(const float* __restrict__ h, const float* __restrict__ W_out,
                const float* __restrict__ b_out, float* __restrict__ out, int N) {
  __shared__ float sWoT[40][65];
  int tid = threadIdx.x;
  for (int i = tid; i < 2560; i += 256) {
    int d = i / 40;
    int c = i - d * 40;
    sWoT[c][d] = W_out[i];
  }
  __syncthreads();
  int gw = (int)((blockIdx.x * blockDim.x + tid) >> 6);
  int nw = (int)((gridDim.x * blockDim.x) >> 6);
  int lane = tid & 63;
  int cc = (lane < 40) ? lane : 39;
  float bias = (lane < 40) ? b_out[lane] : 0.f;
  const float* wrow = &sWoT[cc][0];
  for (int n = gw; n < N; n += nw) {
    int nsg = __builtin_amdgcn_readfirstlane(n);
    const float* hrow = h + (size_t)nsg * 64;  // SGPR base -> s_load
    float acc = bias;
    #pragma unroll
    for (int d = 0; d < 64; d++) acc += hrow[d] * wrow[d];
    float lg = (lane < 40) ? acc : -INFINITY;
    float m = lg;
    #pragma unroll
    for (int off = 32; off; off >>= 1) m = fmaxf(m, __shfl_xor(m, off));
    float e = (lane < 40) ? expf(acc - m) : 0.f;
    float s = e;
    #pragma unroll
    for (int off = 32; off; off >>= 1) s += __shfl_xor(s, off);
    float lse = m + logf(s);
    if (lane < 40) out[(size_t)nsg * 40 + lane] = acc - lse;
  }
}

extern "C" void kernel_launch(void* const* d_in, const int* in_sizes, int n_in,
                              void* d_out, int out_size, void* d_ws, size_t ws_size,
                              hipStream_t stream) {
  const float* V     = (const float*)d_in[0];
  const int*   src   = (const int*)d_in[1];
  const int*   dst   = (const int*)d_in[2];
  const float* W_in  = (const float*)d_in[3];
  const float* b_in  = (const float*)d_in[4];
  const float* W_l   = (const float*)d_in[5];
  const float* b_l   = (const float*)d_in[6];
  const float* gamma = (const float*)d_in[7];
  const float* beta  = (const float*)d_in[8];
  const float* W_out = (const float*)d_in[9];
  const float* b_out = (const float*)d_in[10];
  float* out = (float*)d_out;

  const int N = in_sizes[0] / 128;  // 100000
  const int E = in_sizes[1];        // 1600000
  const int NL = 4;

  char* p = (char*)d_ws;
  auto alloc = [&](size_t bytes) {
    void* r = (void*)p;
    p += (bytes + 255) & ~(size_t)255;
    return r;
  };
  float*          h       = (float*)alloc((size_t)N * 64 * 4);
  float*          hc      = (float*)alloc((size_t)N * 64 * 4);
  unsigned short* hs      = (unsigned short*)alloc((size_t)N * 64 * 2);  // bf16
  int*            bucket  = (int*)alloc((size_t)N * DEG_CAP * 4);
  int*            cnt_src = (int*)alloc((size_t)N * 4);
  int*            cnt_dst = (int*)alloc((size_t)N * 4);
  float*          nrm_src = (float*)alloc((size_t)N * 4);
  float*          nrm_dst = (float*)alloc((size_t)N * 4);
  float*          stats   = (float*)alloc(128 * 4);
  (void)ws_size;

  hipMemsetAsync(cnt_src, 0, (size_t)N * 4, stream);
  hipMemsetAsync(cnt_dst, 0, (size_t)N * 4, stream);

  hist_kernel<<<2048, 256, 0, stream>>>(src, cnt_src, E, N);
  fill_kernel<<<2048, 256, 0, stream>>>(src, dst, cnt_dst, bucket, E, N);
  norms_kernel<<<(N + 255) / 256, 256, 0, stream>>>(cnt_src, cnt_dst, nrm_src, nrm_dst, N);

  input_gemm_kernel<<<(N + 31) / 32, 256, 0, stream>>>(V, W_in, b_in, nrm_src, h, hs, N);

  for (int l = 0; l < NL; l++) {
    hipMemsetAsync(stats, 0, 128 * 4, stream);
    agg_gemm_stats_kernel<<<(N + 63) / 64, 256, 0, stream>>>(
        hs, nrm_dst, cnt_dst, bucket, W_l + (size_t)l * 64 * 64,
        b_l + (size_t)l * 64, hc, stats, N);
    apply_kernel<<<2048, 256, 0, stream>>>(hc, stats, gamma + (size_t)l * 64,
                                           beta + (size_t)l * 64, nrm_src, h, hs, N,
                                           (l < NL - 1) ? 1 : 0);
  }

  out_kernel<<<1024, 256, 0, stream>>>(h, W_out, b_out, out, N);
}

// Round 11
// 951.009 us; speedup vs baseline: 1.2497x; 1.2497x over previous
//
#include <hip/hip_runtime.h>
#include <math.h>

// GCN forward: N=100000, IN_DIM=128, D=64, L=4, C=40, E=1.6M.
// Round 11: REVERT round-10 fusion (it cut gather occupancy 70%->32%,
// 217us vs 115us separate -- latency-bound phase must not share resources
// with the GEMM). Back to round-9 structure, plus:
// (1) agg: 2 nodes/wave, 16 outstanding loads (round-9 agg VGPR=12, occ 70%,
//     VALUBusy 18% -> latency-bound; double per-wave MLP).
// (2) hist merged into fill (same E-scan, src-window filter alongside dst).

#define LEAKY_SLOPE 0.2f
#define BN_EPS 1e-5f
#define DEG_CAP 48

__device__ __forceinline__ unsigned short f2bf(float f) {
  unsigned int x = __float_as_uint(f);
  unsigned int r = (x + 0x7FFFu + ((x >> 16) & 1u)) >> 16;  // RNE
  return (unsigned short)r;
}
__device__ __forceinline__ float bf2f(unsigned short u) {
  return __uint_as_float((unsigned int)u << 16);
}

// ---------------- XCD-windowed fill + src histogram (one E-scan) ----------------
__global__ __launch_bounds__(256, 8)
void fill_hist_kernel(const int* __restrict__ src, const int* __restrict__ dst,
                      int* __restrict__ cnt_src, int* __restrict__ cnt_dst,
                      int* __restrict__ bucket, int E, int N) {
  int bid = blockIdx.x;
  int w = bid & 7;                         // XCD id; window 2.4MB < 4MiB L2
  int chunk = (N + 7) >> 3;
  int lo = w * chunk;
  int hi = min(lo + chunk, N);
  int i = (bid >> 3) * blockDim.x + threadIdx.x;
  int stride = (gridDim.x >> 3) * blockDim.x;
  for (; i < E; i += stride) {
    int s = src[i];
    int d = dst[i];
    if (s >= lo && s < hi) atomicAdd(&cnt_src[s], 1);
    if (d >= lo && d < hi) {
      int pos = atomicAdd(&cnt_dst[d], 1);
      if (pos < DEG_CAP) bucket[d * DEG_CAP + pos] = s;
    }
  }
}

// ---------------- norms from degree counts ----------------
__global__ __launch_bounds__(256, 8)
void norms_kernel(const int* __restrict__ cnt_src, const int* __restrict__ cnt_dst,
                  float* __restrict__ norm_src, float* __restrict__ norm_dst, int N) {
  int i = blockIdx.x * blockDim.x + threadIdx.x;
  if (i < N) {
    norm_src[i] = rsqrtf(fmaxf((float)cnt_src[i], 1.0f));
    norm_dst[i] = rsqrtf(fmaxf((float)cnt_dst[i], 1.0f));
  }
}

// ---------------- input GEMM: h = V @ W_in + b_in (128->64); hs = bf16(h*norm_src) ----
__global__ __launch_bounds__(256) __attribute__((amdgpu_waves_per_eu(3, 4)))
void input_gemm_kernel(const float* __restrict__ V, const float* __restrict__ W_in,
                       const float* __restrict__ b_in, const float* __restrict__ norm_src,
                       float* __restrict__ h, unsigned short* __restrict__ hs, int N) {
  __shared__ __align__(16) float sW[128][64];
  __shared__ __align__(16) float sA[32][132];
  int tid = threadIdx.x;
  int c0 = (tid & 15) * 4;
  int rp = tid >> 4;
  int base = blockIdx.x * 32;

  float4 b4 = *(const float4*)&b_in[c0];

  #pragma unroll
  for (int it = 0; it < 8; it++) {
    int i = tid + it * 256;
    int r = i >> 4, cc = (i & 15) * 4;
    *(float4*)&sW[r][cc] = *(const float4*)&W_in[r * 64 + cc];
  }
  #pragma unroll
  for (int it = 0; it < 4; it++) {
    int i = tid + it * 256;
    int r = i >> 5, cc = (i & 31) * 4;
    int n = base + r;
    float4 v = make_float4(0.f, 0.f, 0.f, 0.f);
    if (n < N) v = *(const float4*)&V[(size_t)n * 128 + cc];
    *(float4*)&sA[r][cc] = v;
  }
  __syncthreads();

  int r0 = rp * 2, r1 = rp * 2 + 1;
  float acc0[4] = {0.f, 0.f, 0.f, 0.f};
  float acc1[4] = {0.f, 0.f, 0.f, 0.f};
  #pragma unroll 4
  for (int d0 = 0; d0 < 128; d0 += 4) {
    float4 wr0 = *(const float4*)&sW[d0 + 0][c0];
    float4 wr1 = *(const float4*)&sW[d0 + 1][c0];
    float4 wr2 = *(const float4*)&sW[d0 + 2][c0];
    float4 wr3 = *(const float4*)&sW[d0 + 3][c0];
    float4 a0 = *(const float4*)&sA[r0][d0];
    float4 a1 = *(const float4*)&sA[r1][d0];
    acc0[0] += a0.x * wr0.x + a0.y * wr1.x + a0.z * wr2.x + a0.w * wr3.x;
    acc0[1] += a0.x * wr0.y + a0.y * wr1.y + a0.z * wr2.y + a0.w * wr3.y;
    acc0[2] += a0.x * wr0.z + a0.y * wr1.z + a0.z * wr2.z + a0.w * wr3.z;
    acc0[3] += a0.x * wr0.w + a0.y * wr1.w + a0.z * wr2.w + a0.w * wr3.w;
    acc1[0] += a1.x * wr0.x + a1.y * wr1.x + a1.z * wr2.x + a1.w * wr3.x;
    acc1[1] += a1.x * wr0.y + a1.y * wr1.y + a1.z * wr2.y + a1.w * wr3.y;
    acc1[2] += a1.x * wr0.z + a1.y * wr1.z + a1.z * wr2.z + a1.w * wr3.z;
    acc1[3] += a1.x * wr0.w + a1.y * wr1.w + a1.z * wr2.w + a1.w * wr3.w;
  }

  int n0 = base + r0, n1 = base + r1;
  if (n0 < N) {
    float4 o = make_float4(acc0[0] + b4.x, acc0[1] + b4.y, acc0[2] + b4.z, acc0[3] + b4.w);
    *(float4*)&h[(size_t)n0 * 64 + c0] = o;
    float ns = norm_src[n0];
    ushort4 s = make_ushort4(f2bf(o.x * ns), f2bf(o.y * ns), f2bf(o.z * ns), f2bf(o.w * ns));
    *(ushort4*)&hs[(size_t)n0 * 64 + c0] = s;
  }
  if (n1 < N) {
    float4 o = make_float4(acc1[0] + b4.x, acc1[1] + b4.y, acc1[2] + b4.z, acc1[3] + b4.w);
    *(float4*)&h[(size_t)n1 * 64 + c0] = o;
    float ns = norm_src[n1];
    ushort4 s = make_ushort4(f2bf(o.x * ns), f2bf(o.y * ns), f2bf(o.z * ns), f2bf(o.w * ns));
    *(ushort4*)&hs[(size_t)n1 * 64 + c0] = s;
  }
}

// ---------------- aggregation: 2 nodes per wave, 16 outstanding gather loads ----
__global__ __launch_bounds__(256, 8)
void agg_kernel(const unsigned short* __restrict__ hs, const float* __restrict__ norm_dst,
                const int* __restrict__ cnt_dst, const int* __restrict__ bucket,
                float* __restrict__ agg, int N) {
  int wpair = __builtin_amdgcn_readfirstlane(blockIdx.x * 4 + (threadIdx.x >> 6));
  int lane = threadIdx.x & 63;
  int n0 = wpair * 2;
  int n1 = wpair * 2 + 1;
  if (n0 >= N) return;
  bool has1 = (n1 < N);
  int len0 = cnt_dst[n0];
  int len1 = has1 ? cnt_dst[n1] : 0;
  const int* bkt0 = bucket + (size_t)n0 * DEG_CAP;  // SGPR base -> s_load
  const int* bkt1 = bucket + (size_t)n1 * DEG_CAP;
  float a[8] = {0.f, 0.f, 0.f, 0.f, 0.f, 0.f, 0.f, 0.f};
  float b[8] = {0.f, 0.f, 0.f, 0.f, 0.f, 0.f, 0.f, 0.f};
  int maxlen = max(len0, len1);
  for (int j = 0; j < maxlen; j += 8) {
    int sa[8], sb[8];
    #pragma unroll
    for (int k = 0; k < 8; k++) sa[k] = (j + k < len0) ? bkt0[j + k] : 0;
    #pragma unroll
    for (int k = 0; k < 8; k++) sb[k] = (j + k < len1) ? bkt1[j + k] : 0;
    unsigned short va[8], vb[8];
    #pragma unroll
    for (int k = 0; k < 8; k++) va[k] = (j + k < len0) ? hs[(size_t)sa[k] * 64 + lane] : 0;
    #pragma unroll
    for (int k = 0; k < 8; k++) vb[k] = (j + k < len1) ? hs[(size_t)sb[k] * 64 + lane] : 0;
    #pragma unroll
    for (int k = 0; k < 8; k++) a[k] += bf2f(va[k]);
    #pragma unroll
    for (int k = 0; k < 8; k++) b[k] += bf2f(vb[k]);
  }
  float acc0 = ((a[0] + a[1]) + (a[2] + a[3])) + ((a[4] + a[5]) + (a[6] + a[7]));
  agg[(size_t)n0 * 64 + lane] = acc0 * norm_dst[n0];
  if (has1) {
    float acc1 = ((b[0] + b[1]) + (b[2] + b[3])) + ((b[4] + b[5]) + (b[6] + b[7]));
    agg[(size_t)n1 * 64 + lane] = acc1 * norm_dst[n1];
  }
}

// ---------------- layer GEMM + BN stats: hc = agg @ W + b; stats += (sum,sumsq) ----
__global__ __launch_bounds__(256) __attribute__((amdgpu_waves_per_eu(4, 4)))
void gemm_stats_kernel(const float* __restrict__ agg, const float* __restrict__ W,
                       const float* __restrict__ b, float* __restrict__ hc,
                       float* __restrict__ stats, int N) {
  __shared__ __align__(16) float sW[64][64];
  __shared__ __align__(16) float sA[64][68];
  int tid = threadIdx.x;
  int lane = tid & 63;
  int wv = tid >> 6;
  int cg = lane & 15;
  int ng = lane >> 4;
  int nrow0 = wv * 16 + ng * 4;
  int base = blockIdx.x * 64;

  #pragma unroll
  for (int it = 0; it < 4; it++) {
    int i = tid + it * 256;
    int r = i >> 4, c4 = (i & 15) * 4;
    *(float4*)&sW[r][c4] = *(const float4*)&W[r * 64 + c4];
  }
  #pragma unroll
  for (int it = 0; it < 4; it++) {
    int i = tid + it * 256;
    int r = i >> 4, c4 = (i & 15) * 4;
    int n = base + r;
    float4 v = make_float4(0.f, 0.f, 0.f, 0.f);
    if (n < N) v = *(const float4*)&agg[(size_t)n * 64 + c4];
    *(float4*)&sA[r][c4] = v;
  }
  __syncthreads();

  float4 b4 = *(const float4*)&b[cg * 4];

  float acc[4][4];
  #pragma unroll
  for (int i = 0; i < 4; i++)
    #pragma unroll
    for (int c = 0; c < 4; c++) acc[i][c] = 0.f;

  #pragma unroll 4
  for (int d0 = 0; d0 < 64; d0 += 4) {
    float4 wr0 = *(const float4*)&sW[d0 + 0][cg * 4];
    float4 wr1 = *(const float4*)&sW[d0 + 1][cg * 4];
    float4 wr2 = *(const float4*)&sW[d0 + 2][cg * 4];
    float4 wr3 = *(const float4*)&sW[d0 + 3][cg * 4];
    #pragma unroll
    for (int i = 0; i < 4; i++) {
      float4 av = *(const float4*)&sA[nrow0 + i][d0];
      acc[i][0] += av.x * wr0.x + av.y * wr1.x + av.z * wr2.x + av.w * wr3.x;
      acc[i][1] += av.x * wr0.y + av.y * wr1.y + av.z * wr2.y + av.w * wr3.y;
      acc[i][2] += av.x * wr0.z + av.y * wr1.z + av.z * wr2.z + av.w * wr3.z;
      acc[i][3] += av.x * wr0.w + av.y * wr1.w + av.z * wr2.w + av.w * wr3.w;
    }
  }

  float st_s0=0.f,st_s1=0.f,st_s2=0.f,st_s3=0.f;
  float st_q0=0.f,st_q1=0.f,st_q2=0.f,st_q3=0.f;
  #pragma unroll
  for (int i = 0; i < 4; i++) {
    int n = base + nrow0 + i;
    if (n < N) {
      float4 o;
      o.x = acc[i][0] + b4.x; o.y = acc[i][1] + b4.y;
      o.z = acc[i][2] + b4.z; o.w = acc[i][3] + b4.w;
      *(float4*)&hc[(size_t)n * 64 + cg * 4] = o;
      st_s0 += o.x; st_s1 += o.y; st_s2 += o.z; st_s3 += o.w;
      st_q0 += o.x * o.x; st_q1 += o.y * o.y;
      st_q2 += o.z * o.z; st_q3 += o.w * o.w;
    }
  }

  __syncthreads();
  int rr = wv * 4 + ng;
  *(float4*)&sA[rr][cg * 4]      = make_float4(st_s0, st_s1, st_s2, st_s3);
  *(float4*)&sA[16 + rr][cg * 4] = make_float4(st_q0, st_q1, st_q2, st_q3);
  __syncthreads();
  if (tid < 64) {
    float s = 0.f, q = 0.f;
    #pragma unroll
    for (int r = 0; r < 16; r++) { s += sA[r][tid]; q += sA[16 + r][tid]; }
    atomicAdd(&stats[tid], s);
    atomicAdd(&stats[64 + tid], q);
  }
}

// ---------------- fused BN finalize + apply + residual + bf16 pre-scale ----------------
__global__ __launch_bounds__(256, 8)
void apply_kernel(const float* __restrict__ hc, const float* __restrict__ stats,
                  const float* __restrict__ gamma, const float* __restrict__ beta,
                  const float* __restrict__ norm_src, float* __restrict__ h,
                  unsigned short* __restrict__ hs, int N, int write_hs) {
  __shared__ float s_scale[64];
  __shared__ float s_shift[64];
  int tid = threadIdx.x;
  if (tid < 64) {
    float s = stats[tid];
    float ss = stats[64 + tid];
    float invN = 1.0f / (float)N;
    float mean = s * invN;
    float var = fmaxf(ss * invN - mean * mean, 0.0f);
    float scale = gamma[tid] * rsqrtf(var + BN_EPS);
    s_scale[tid] = scale;
    s_shift[tid] = beta[tid] - mean * scale;
  }
  __syncthreads();
  int total4 = N * 16;
  int i = blockIdx.x * blockDim.x + threadIdx.x;
  int stride = gridDim.x * blockDim.x;
  for (; i < total4; i += stride) {
    float4 v = ((const float4*)hc)[i];
    float4 r = ((const float4*)h)[i];
    int cb = (i * 4) & 63;
    int n = i >> 4;
    float o0 = v.x * s_scale[cb + 0] + s_shift[cb + 0];
    float o1 = v.y * s_scale[cb + 1] + s_shift[cb + 1];
    float o2 = v.z * s_scale[cb + 2] + s_shift[cb + 2];
    float o3 = v.w * s_scale[cb + 3] + s_shift[cb + 3];
    o0 = (o0 >= 0.f) ? o0 : LEAKY_SLOPE * o0;
    o1 = (o1 >= 0.f) ? o1 : LEAKY_SLOPE * o1;
    o2 = (o2 >= 0.f) ? o2 : LEAKY_SLOPE * o2;
    o3 = (o3 >= 0.f) ? o3 : LEAKY_SLOPE * o3;
    float4 oh;
    oh.x = o0 + r.x; oh.y = o1 + r.y; oh.z = o2 + r.z; oh.w = o3 + r.w;
    ((float4*)h)[i] = oh;
    if (write_hs) {
      float nsc = norm_src[n];
      ushort4 os = make_ushort4(f2bf(oh.x * nsc), f2bf(oh.y * nsc),
                                f2bf(oh.z * nsc), f2bf(oh.w * nsc));
      ((ushort4*)hs)[i] = os;
    }
  }
}

// ---------------- output: logits = h @ W_out + b_out; log_softmax ----------------
__global__ __launch_bounds__(256, 4)
void out_kernel(const float* __restrict__ h, const float* __restrict__ W_out,
                const float* __restrict__ b_out, float* __restrict__ out, int N) {
  __shared__ float sWoT[40][65];
  int tid = threadIdx.x;
  for (int i = tid; i < 2560; i += 256) {
    int d = i / 40;
    int c = i - d * 40;
    sWoT[c][d] = W_out[i];
  }
  __syncthreads();
  int gw = (int)((blockIdx.x * blockDim.x + tid) >> 6);
  int nw = (int)((gridDim.x * blockDim.x) >> 6);
  int lane = tid & 63;
  int cc = (lane < 40) ? lane : 39;
  float bias = (lane < 40) ? b_out[lane] : 0.f;
  const float* wrow = &sWoT[cc][0];
  for (int n = gw; n < N; n += nw) {
    int nsg = __builtin_amdgcn_readfirstlane(n);
    const float* hrow = h + (size_t)nsg * 64;  // SGPR base -> s_load
    float acc = bias;
    #pragma unroll
    for (int d = 0; d < 64; d++) acc += hrow[d] * wrow[d];
    float lg = (lane < 40) ? acc : -INFINITY;
    float m = lg;
    #pragma unroll
    for (int off = 32; off; off >>= 1) m = fmaxf(m, __shfl_xor(m, off));
    float e = (lane < 40) ? expf(acc - m) : 0.f;
    float s = e;
    #pragma unroll
    for (int off = 32; off; off >>= 1) s += __shfl_xor(s, off);
    float lse = m + logf(s);
    if (lane < 40) out[(size_t)nsg * 40 + lane] = acc - lse;
  }
}

extern "C" void kernel_launch(void* const* d_in, const int* in_sizes, int n_in,
                              void* d_out, int out_size, void* d_ws, size_t ws_size,
                              hipStream_t stream) {
  const float* V     = (const float*)d_in[0];
  const int*   src   = (const int*)d_in[1];
  const int*   dst   = (const int*)d_in[2];
  const float* W_in  = (const float*)d_in[3];
  const float* b_in  = (const float*)d_in[4];
  const float* W_l   = (const float*)d_in[5];
  const float* b_l   = (const float*)d_in[6];
  const float* gamma = (const float*)d_in[7];
  const float* beta  = (const float*)d_in[8];
  const float* W_out = (const float*)d_in[9];
  const float* b_out = (const float*)d_in[10];
  float* out = (float*)d_out;

  const int N = in_sizes[0] / 128;  // 100000
  const int E = in_sizes[1];        // 1600000
  const int NL = 4;

  char* p = (char*)d_ws;
  auto alloc = [&](size_t bytes) {
    void* r = (void*)p;
    p += (bytes + 255) & ~(size_t)255;
    return r;
  };
  float*          h       = (float*)alloc((size_t)N * 64 * 4);
  float*          agg     = (float*)alloc((size_t)N * 64 * 4);
  float*          hc      = (float*)alloc((size_t)N * 64 * 4);
  unsigned short* hs      = (unsigned short*)alloc((size_t)N * 64 * 2);  // bf16
  int*            bucket  = (int*)alloc((size_t)N * DEG_CAP * 4);
  int*            cnt_src = (int*)alloc((size_t)N * 4);
  int*            cnt_dst = (int*)alloc((size_t)N * 4);
  float*          nrm_src = (float*)alloc((size_t)N * 4);
  float*          nrm_dst = (float*)alloc((size_t)N * 4);
  float*          stats   = (float*)alloc(128 * 4);
  (void)ws_size;

  hipMemsetAsync(cnt_src, 0, (size_t)N * 4, stream);
  hipMemsetAsync(cnt_dst, 0, (size_t)N * 4, stream);

  fill_hist_kernel<<<2048, 256, 0, stream>>>(src, dst, cnt_src, cnt_dst, bucket, E, N);
  norms_kernel<<<(N + 255) / 256, 256, 0, stream>>>(cnt_src, cnt_dst, nrm_src, nrm_dst, N);

  input_gemm_kernel<<<(N + 31) / 32, 256, 0, stream>>>(V, W_in, b_in, nrm_src, h, hs, N);

  for (int l = 0; l < NL; l++) {
    agg_kernel<<<(N + 7) / 8, 256, 0, stream>>>(hs, nrm_dst, cnt_dst, bucket, agg, N);
    hipMemsetAsync(stats, 0, 128 * 4, stream);
    gemm_stats_kernel<<<(N + 63) / 64, 256, 0, stream>>>(agg, W_l + (size_t)l * 64 * 64,
                                                         b_l + (size_t)l * 64, hc, stats, N);
    apply_kernel<<<2048, 256, 0, stream>>>(hc, stats, gamma + (size_t)l * 64,
                                           beta + (size_t)l * 64, nrm_src, h, hs, N,
                                           (l < NL - 1) ? 1 : 0);
  }

  out_kernel<<<1024, 256, 0, stream>>>(h, W_out, b_out, out, N);
}

// Round 12
// 893.039 us; speedup vs baseline: 1.3308x; 1.0649x over previous
//
#include <hip/hip_runtime.h>
#include <math.h>

// GCN forward: N=100000, IN_DIM=128, D=64, L=4, C=40, E=1.6M.
// Round 12: consolidate. (1) agg reverted to round-9 1-node/wave (round-11's
// 2-node/wave was +9us/dispatch: agg is request-rate-bound, not wave-latency
// bound). (2) stats[4][128] zeroed once in norms -> 4 fewer memset launches.
// (3) last-layer apply fused with out (no h/hs write for l=3: -50MB).
// (4) persistent loops in input_gemm/gemm_stats (W staged once per block).

#define LEAKY_SLOPE 0.2f
#define BN_EPS 1e-5f
#define DEG_CAP 48

__device__ __forceinline__ unsigned short f2bf(float f) {
  unsigned int x = __float_as_uint(f);
  unsigned int r = (x + 0x7FFFu + ((x >> 16) & 1u)) >> 16;  // RNE
  return (unsigned short)r;
}
__device__ __forceinline__ float bf2f(unsigned short u) {
  return __uint_as_float((unsigned int)u << 16);
}

// ---------------- XCD-windowed fill + src histogram (one E-scan) ----------------
__global__ __launch_bounds__(256, 8)
void fill_hist_kernel(const int* __restrict__ src, const int* __restrict__ dst,
                      int* __restrict__ cnt_src, int* __restrict__ cnt_dst,
                      int* __restrict__ bucket, int E, int N) {
  int bid = blockIdx.x;
  int w = bid & 7;                         // XCD id; window 2.4MB < 4MiB L2
  int chunk = (N + 7) >> 3;
  int lo = w * chunk;
  int hi = min(lo + chunk, N);
  int i = (bid >> 3) * blockDim.x + threadIdx.x;
  int stride = (gridDim.x >> 3) * blockDim.x;
  for (; i < E; i += stride) {
    int s = src[i];
    int d = dst[i];
    if (s >= lo && s < hi) atomicAdd(&cnt_src[s], 1);
    if (d >= lo && d < hi) {
      int pos = atomicAdd(&cnt_dst[d], 1);
      if (pos < DEG_CAP) bucket[d * DEG_CAP + pos] = s;
    }
  }
}

// ---------------- norms from degree counts; also zero the 4 stats buffers ----------------
__global__ __launch_bounds__(256, 8)
void norms_kernel(const int* __restrict__ cnt_src, const int* __restrict__ cnt_dst,
                  float* __restrict__ norm_src, float* __restrict__ norm_dst,
                  float* __restrict__ stats, int N) {
  int i = blockIdx.x * blockDim.x + threadIdx.x;
  if (blockIdx.x == 0) {
    if (threadIdx.x < 256) {
      stats[threadIdx.x] = 0.f;
      stats[256 + threadIdx.x] = 0.f;
    }
  }
  if (i < N) {
    norm_src[i] = rsqrtf(fmaxf((float)cnt_src[i], 1.0f));
    norm_dst[i] = rsqrtf(fmaxf((float)cnt_dst[i], 1.0f));
  }
}

// ---------------- input GEMM: h = V @ W_in + b_in (128->64); hs = bf16(h*norm_src) ----
// Persistent: W_in staged once per block; tiles looped.
__global__ __launch_bounds__(256) __attribute__((amdgpu_waves_per_eu(3, 4)))
void input_gemm_kernel(const float* __restrict__ V, const float* __restrict__ W_in,
                       const float* __restrict__ b_in, const float* __restrict__ norm_src,
                       float* __restrict__ h, unsigned short* __restrict__ hs, int N) {
  __shared__ __align__(16) float sW[128][64];
  __shared__ __align__(16) float sA[32][132];
  int tid = threadIdx.x;
  int c0 = (tid & 15) * 4;
  int rp = tid >> 4;

  float4 b4 = *(const float4*)&b_in[c0];

  #pragma unroll
  for (int it = 0; it < 8; it++) {
    int i = tid + it * 256;
    int r = i >> 4, cc = (i & 15) * 4;
    *(float4*)&sW[r][cc] = *(const float4*)&W_in[r * 64 + cc];
  }

  for (int base = blockIdx.x * 32; base < N; base += gridDim.x * 32) {
    __syncthreads();   // previous tile's sA reads done (also covers sW first use)
    #pragma unroll
    for (int it = 0; it < 4; it++) {
      int i = tid + it * 256;
      int r = i >> 5, cc = (i & 31) * 4;
      int n = base + r;
      float4 v = make_float4(0.f, 0.f, 0.f, 0.f);
      if (n < N) v = *(const float4*)&V[(size_t)n * 128 + cc];
      *(float4*)&sA[r][cc] = v;
    }
    __syncthreads();

    int r0 = rp * 2, r1 = rp * 2 + 1;
    float acc0[4] = {0.f, 0.f, 0.f, 0.f};
    float acc1[4] = {0.f, 0.f, 0.f, 0.f};
    #pragma unroll 4
    for (int d0 = 0; d0 < 128; d0 += 4) {
      float4 wr0 = *(const float4*)&sW[d0 + 0][c0];
      float4 wr1 = *(const float4*)&sW[d0 + 1][c0];
      float4 wr2 = *(const float4*)&sW[d0 + 2][c0];
      float4 wr3 = *(const float4*)&sW[d0 + 3][c0];
      float4 a0 = *(const float4*)&sA[r0][d0];
      float4 a1 = *(const float4*)&sA[r1][d0];
      acc0[0] += a0.x * wr0.x + a0.y * wr1.x + a0.z * wr2.x + a0.w * wr3.x;
      acc0[1] += a0.x * wr0.y + a0.y * wr1.y + a0.z * wr2.y + a0.w * wr3.y;
      acc0[2] += a0.x * wr0.z + a0.y * wr1.z + a0.z * wr2.z + a0.w * wr3.z;
      acc0[3] += a0.x * wr0.w + a0.y * wr1.w + a0.z * wr2.w + a0.w * wr3.w;
      acc1[0] += a1.x * wr0.x + a1.y * wr1.x + a1.z * wr2.x + a1.w * wr3.x;
      acc1[1] += a1.x * wr0.y + a1.y * wr1.y + a1.z * wr2.y + a1.w * wr3.y;
      acc1[2] += a1.x * wr0.z + a1.y * wr1.z + a1.z * wr2.z + a1.w * wr3.z;
      acc1[3] += a1.x * wr0.w + a1.y * wr1.w + a1.z * wr2.w + a1.w * wr3.w;
    }

    int n0 = base + r0, n1 = base + r1;
    if (n0 < N) {
      float4 o = make_float4(acc0[0] + b4.x, acc0[1] + b4.y, acc0[2] + b4.z, acc0[3] + b4.w);
      *(float4*)&h[(size_t)n0 * 64 + c0] = o;
      float ns = norm_src[n0];
      ushort4 s = make_ushort4(f2bf(o.x * ns), f2bf(o.y * ns), f2bf(o.z * ns), f2bf(o.w * ns));
      *(ushort4*)&hs[(size_t)n0 * 64 + c0] = s;
    }
    if (n1 < N) {
      float4 o = make_float4(acc1[0] + b4.x, acc1[1] + b4.y, acc1[2] + b4.z, acc1[3] + b4.w);
      *(float4*)&h[(size_t)n1 * 64 + c0] = o;
      float ns = norm_src[n1];
      ushort4 s = make_ushort4(f2bf(o.x * ns), f2bf(o.y * ns), f2bf(o.z * ns), f2bf(o.w * ns));
      *(ushort4*)&hs[(size_t)n1 * 64 + c0] = s;
    }
  }
}

// ---------------- aggregation (round-9 proven): wave/node, 8-deep MLP, bf16 gather ----
__global__ __launch_bounds__(256, 8)
void agg_kernel(const unsigned short* __restrict__ hs, const float* __restrict__ norm_dst,
                const int* __restrict__ cnt_dst, const int* __restrict__ bucket,
                float* __restrict__ agg, int N) {
  int wid = __builtin_amdgcn_readfirstlane(blockIdx.x * 4 + (threadIdx.x >> 6));
  int lane = threadIdx.x & 63;
  if (wid >= N) return;
  int len = cnt_dst[wid];
  float nd = norm_dst[wid];
  const int* bkt = bucket + wid * DEG_CAP;  // SGPR base -> s_load indices
  float a0=0.f,a1=0.f,a2=0.f,a3=0.f,a4=0.f,a5=0.f,a6=0.f,a7=0.f;
  for (int j = 0; j < len; j += 8) {
    int s0=0,s1=0,s2=0,s3=0,s4=0,s5=0,s6=0,s7=0;
    if (j + 0 < len) s0 = bkt[j + 0];
    if (j + 1 < len) s1 = bkt[j + 1];
    if (j + 2 < len) s2 = bkt[j + 2];
    if (j + 3 < len) s3 = bkt[j + 3];
    if (j + 4 < len) s4 = bkt[j + 4];
    if (j + 5 < len) s5 = bkt[j + 5];
    if (j + 6 < len) s6 = bkt[j + 6];
    if (j + 7 < len) s7 = bkt[j + 7];
    unsigned short h0=0,h1=0,h2=0,h3=0,h4=0,h5=0,h6=0,h7=0;
    if (j + 0 < len) h0 = hs[(size_t)s0 * 64 + lane];
    if (j + 1 < len) h1 = hs[(size_t)s1 * 64 + lane];
    if (j + 2 < len) h2 = hs[(size_t)s2 * 64 + lane];
    if (j + 3 < len) h3 = hs[(size_t)s3 * 64 + lane];
    if (j + 4 < len) h4 = hs[(size_t)s4 * 64 + lane];
    if (j + 5 < len) h5 = hs[(size_t)s5 * 64 + lane];
    if (j + 6 < len) h6 = hs[(size_t)s6 * 64 + lane];
    if (j + 7 < len) h7 = hs[(size_t)s7 * 64 + lane];
    if (j + 0 < len) a0 += bf2f(h0);
    if (j + 1 < len) a1 += bf2f(h1);
    if (j + 2 < len) a2 += bf2f(h2);
    if (j + 3 < len) a3 += bf2f(h3);
    if (j + 4 < len) a4 += bf2f(h4);
    if (j + 5 < len) a5 += bf2f(h5);
    if (j + 6 < len) a6 += bf2f(h6);
    if (j + 7 < len) a7 += bf2f(h7);
  }
  float acc = ((a0 + a1) + (a2 + a3)) + ((a4 + a5) + (a6 + a7));
  agg[(size_t)wid * 64 + lane] = acc * nd;
}

// ---------------- layer GEMM + BN stats (persistent tiles) ----------------
__global__ __launch_bounds__(256) __attribute__((amdgpu_waves_per_eu(4, 4)))
void gemm_stats_kernel(const float* __restrict__ agg, const float* __restrict__ W,
                       const float* __restrict__ b, float* __restrict__ hc,
                       float* __restrict__ stats, int N) {
  __shared__ __align__(16) float sW[64][64];
  __shared__ __align__(16) float sA[64][68];
  int tid = threadIdx.x;
  int lane = tid & 63;
  int wv = tid >> 6;
  int cg = lane & 15;
  int ng = lane >> 4;
  int nrow0 = wv * 16 + ng * 4;

  #pragma unroll
  for (int it = 0; it < 4; it++) {
    int i = tid + it * 256;
    int r = i >> 4, c4 = (i & 15) * 4;
    *(float4*)&sW[r][c4] = *(const float4*)&W[r * 64 + c4];
  }

  float4 b4 = *(const float4*)&b[cg * 4];

  float st_s0=0.f,st_s1=0.f,st_s2=0.f,st_s3=0.f;
  float st_q0=0.f,st_q1=0.f,st_q2=0.f,st_q3=0.f;

  for (int base = blockIdx.x * 64; base < N; base += gridDim.x * 64) {
    __syncthreads();   // previous tile's sA reads done (also covers sW first use)
    #pragma unroll
    for (int it = 0; it < 4; it++) {
      int i = tid + it * 256;
      int r = i >> 4, c4 = (i & 15) * 4;
      int n = base + r;
      float4 v = make_float4(0.f, 0.f, 0.f, 0.f);
      if (n < N) v = *(const float4*)&agg[(size_t)n * 64 + c4];
      *(float4*)&sA[r][c4] = v;
    }
    __syncthreads();

    float acc[4][4];
    #pragma unroll
    for (int i = 0; i < 4; i++)
      #pragma unroll
      for (int c = 0; c < 4; c++) acc[i][c] = 0.f;

    #pragma unroll 4
    for (int d0 = 0; d0 < 64; d0 += 4) {
      float4 wr0 = *(const float4*)&sW[d0 + 0][cg * 4];
      float4 wr1 = *(const float4*)&sW[d0 + 1][cg * 4];
      float4 wr2 = *(const float4*)&sW[d0 + 2][cg * 4];
      float4 wr3 = *(const float4*)&sW[d0 + 3][cg * 4];
      #pragma unroll
      for (int i = 0; i < 4; i++) {
        float4 av = *(const float4*)&sA[nrow0 + i][d0];
        acc[i][0] += av.x * wr0.x + av.y * wr1.x + av.z * wr2.x + av.w * wr3.x;
        acc[i][1] += av.x * wr0.y + av.y * wr1.y + av.z * wr2.y + av.w * wr3.y;
        acc[i][2] += av.x * wr0.z + av.y * wr1.z + av.z * wr2.z + av.w * wr3.z;
        acc[i][3] += av.x * wr0.w + av.y * wr1.w + av.z * wr2.w + av.w * wr3.w;
      }
    }

    #pragma unroll
    for (int i = 0; i < 4; i++) {
      int n = base + nrow0 + i;
      if (n < N) {
        float4 o;
        o.x = acc[i][0] + b4.x; o.y = acc[i][1] + b4.y;
        o.z = acc[i][2] + b4.z; o.w = acc[i][3] + b4.w;
        *(float4*)&hc[(size_t)n * 64 + cg * 4] = o;
        st_s0 += o.x; st_s1 += o.y; st_s2 += o.z; st_s3 += o.w;
        st_q0 += o.x * o.x; st_q1 += o.y * o.y;
        st_q2 += o.z * o.z; st_q3 += o.w * o.w;
      }
    }
  }

  // block reduction of stats (reuse sA): rows 0..15 sums, 16..31 sumsq
  __syncthreads();
  int rr = wv * 4 + ng;
  *(float4*)&sA[rr][cg * 4]      = make_float4(st_s0, st_s1, st_s2, st_s3);
  *(float4*)&sA[16 + rr][cg * 4] = make_float4(st_q0, st_q1, st_q2, st_q3);
  __syncthreads();
  if (tid < 64) {
    float s = 0.f, q = 0.f;
    #pragma unroll
    for (int r = 0; r < 16; r++) { s += sA[r][tid]; q += sA[16 + r][tid]; }
    atomicAdd(&stats[tid], s);
    atomicAdd(&stats[64 + tid], q);
  }
}

// ---------------- fused BN finalize + apply + residual + bf16 pre-scale (layers 0..2) ----
__global__ __launch_bounds__(256, 8)
void apply_kernel(const float* __restrict__ hc, const float* __restrict__ stats,
                  const float* __restrict__ gamma, const float* __restrict__ beta,
                  const float* __restrict__ norm_src, float* __restrict__ h,
                  unsigned short* __restrict__ hs, int N) {
  __shared__ float s_scale[64];
  __shared__ float s_shift[64];
  int tid = threadIdx.x;
  if (tid < 64) {
    float s = stats[tid];
    float ss = stats[64 + tid];
    float invN = 1.0f / (float)N;
    float mean = s * invN;
    float var = fmaxf(ss * invN - mean * mean, 0.0f);
    float scale = gamma[tid] * rsqrtf(var + BN_EPS);
    s_scale[tid] = scale;
    s_shift[tid] = beta[tid] - mean * scale;
  }
  __syncthreads();
  int total4 = N * 16;
  int i = blockIdx.x * blockDim.x + threadIdx.x;
  int stride = gridDim.x * blockDim.x;
  for (; i < total4; i += stride) {
    float4 v = ((const float4*)hc)[i];
    float4 r = ((const float4*)h)[i];
    int cb = (i * 4) & 63;
    int n = i >> 4;
    float o0 = v.x * s_scale[cb + 0] + s_shift[cb + 0];
    float o1 = v.y * s_scale[cb + 1] + s_shift[cb + 1];
    float o2 = v.z * s_scale[cb + 2] + s_shift[cb + 2];
    float o3 = v.w * s_scale[cb + 3] + s_shift[cb + 3];
    o0 = (o0 >= 0.f) ? o0 : LEAKY_SLOPE * o0;
    o1 = (o1 >= 0.f) ? o1 : LEAKY_SLOPE * o1;
    o2 = (o2 >= 0.f) ? o2 : LEAKY_SLOPE * o2;
    o3 = (o3 >= 0.f) ? o3 : LEAKY_SLOPE * o3;
    float4 oh;
    oh.x = o0 + r.x; oh.y = o1 + r.y; oh.z = o2 + r.z; oh.w = o3 + r.w;
    ((float4*)h)[i] = oh;
    float nsc = norm_src[n];
    ushort4 os = make_ushort4(f2bf(oh.x * nsc), f2bf(oh.y * nsc),
                              f2bf(oh.z * nsc), f2bf(oh.w * nsc));
    ((ushort4*)hs)[i] = os;
  }
}

// ---------------- fused last-layer apply + output head ----------------
// Wave per node: BN+leaky+residual in registers, row through LDS, logits +
// log_softmax. Never materializes layer-3 h/hs.
__global__ __launch_bounds__(256, 4)
void out_fused_kernel(const float* __restrict__ hc, const float* __restrict__ stats,
                      const float* __restrict__ gamma, const float* __restrict__ beta,
                      const float* __restrict__ h, const float* __restrict__ W_out,
                      const float* __restrict__ b_out, float* __restrict__ out, int N) {
  __shared__ float sWoT[40][65];   // sWoT[c][d] = W_out[d][c]
  __shared__ float s_scale[64];
  __shared__ float s_shift[64];
  __shared__ float sH[4][64];
  int tid = threadIdx.x;
  for (int i = tid; i < 2560; i += 256) {
    int d = i / 40;
    int c = i - d * 40;
    sWoT[c][d] = W_out[i];
  }
  if (tid < 64) {
    float s = stats[tid];
    float ss = stats[64 + tid];
    float invN = 1.0f / (float)N;
    float mean = s * invN;
    float var = fmaxf(ss * invN - mean * mean, 0.0f);
    float scale = gamma[tid] * rsqrtf(var + BN_EPS);
    s_scale[tid] = scale;
    s_shift[tid] = beta[tid] - mean * scale;
  }
  __syncthreads();
  int wv = tid >> 6;
  int lane = tid & 63;
  int gw = blockIdx.x * 4 + wv;
  int nw = gridDim.x * 4;
  int cc = (lane < 40) ? lane : 39;
  float bias = (lane < 40) ? b_out[lane] : 0.f;
  for (int n = gw; n < N; n += nw) {
    float v = hc[(size_t)n * 64 + lane];
    float o = v * s_scale[lane] + s_shift[lane];
    o = (o >= 0.f) ? o : LEAKY_SLOPE * o;
    float oh = o + h[(size_t)n * 64 + lane];
    sH[wv][lane] = oh;
    __builtin_amdgcn_wave_barrier();   // order LDS write vs reads (same wave)
    float acc = bias;
    #pragma unroll
    for (int d = 0; d < 64; d++) acc += sH[wv][d] * sWoT[cc][d];
    float lg = (lane < 40) ? acc : -INFINITY;
    float m = lg;
    #pragma unroll
    for (int off = 32; off; off >>= 1) m = fmaxf(m, __shfl_xor(m, off));
    float e = (lane < 40) ? expf(acc - m) : 0.f;
    float s = e;
    #pragma unroll
    for (int off = 32; off; off >>= 1) s += __shfl_xor(s, off);
    float lse = m + logf(s);
    if (lane < 40) out[(size_t)n * 40 + lane] = acc - lse;
    __builtin_amdgcn_wave_barrier();   // keep sH write of next iter ordered
  }
}

extern "C" void kernel_launch(void* const* d_in, const int* in_sizes, int n_in,
                              void* d_out, int out_size, void* d_ws, size_t ws_size,
                              hipStream_t stream) {
  const float* V     = (const float*)d_in[0];
  const int*   src   = (const int*)d_in[1];
  const int*   dst   = (const int*)d_in[2];
  const float* W_in  = (const float*)d_in[3];
  const float* b_in  = (const float*)d_in[4];
  const float* W_l   = (const float*)d_in[5];
  const float* b_l   = (const float*)d_in[6];
  const float* gamma = (const float*)d_in[7];
  const float* beta  = (const float*)d_in[8];
  const float* W_out = (const float*)d_in[9];
  const float* b_out = (const float*)d_in[10];
  float* out = (float*)d_out;

  const int N = in_sizes[0] / 128;  // 100000
  const int E = in_sizes[1];        // 1600000
  const int NL = 4;

  char* p = (char*)d_ws;
  auto alloc = [&](size_t bytes) {
    void* r = (void*)p;
    p += (bytes + 255) & ~(size_t)255;
    return r;
  };
  float*          h       = (float*)alloc((size_t)N * 64 * 4);
  float*          agg     = (float*)alloc((size_t)N * 64 * 4);
  float*          hc      = (float*)alloc((size_t)N * 64 * 4);
  unsigned short* hs      = (unsigned short*)alloc((size_t)N * 64 * 2);  // bf16
  int*            bucket  = (int*)alloc((size_t)N * DEG_CAP * 4);
  int*            cnt_src = (int*)alloc((size_t)N * 4);
  int*            cnt_dst = (int*)alloc((size_t)N * 4);
  float*          nrm_src = (float*)alloc((size_t)N * 4);
  float*          nrm_dst = (float*)alloc((size_t)N * 4);
  float*          stats   = (float*)alloc(4 * 128 * 4);   // per-layer
  (void)ws_size;

  hipMemsetAsync(cnt_src, 0, (size_t)N * 4, stream);
  hipMemsetAsync(cnt_dst, 0, (size_t)N * 4, stream);

  fill_hist_kernel<<<2048, 256, 0, stream>>>(src, dst, cnt_src, cnt_dst, bucket, E, N);
  norms_kernel<<<(N + 255) / 256, 256, 0, stream>>>(cnt_src, cnt_dst, nrm_src, nrm_dst,
                                                    stats, N);

  input_gemm_kernel<<<1024, 256, 0, stream>>>(V, W_in, b_in, nrm_src, h, hs, N);

  for (int l = 0; l < NL; l++) {
    float* statl = stats + (size_t)l * 128;
    agg_kernel<<<(N + 3) / 4, 256, 0, stream>>>(hs, nrm_dst, cnt_dst, bucket, agg, N);
    gemm_stats_kernel<<<1024, 256, 0, stream>>>(agg, W_l + (size_t)l * 64 * 64,
                                                b_l + (size_t)l * 64, hc, statl, N);
    if (l < NL - 1) {
      apply_kernel<<<2048, 256, 0, stream>>>(hc, statl, gamma + (size_t)l * 64,
                                             beta + (size_t)l * 64, nrm_src, h, hs, N);
    } else {
      out_fused_kernel<<<2048, 256, 0, stream>>>(hc, statl, gamma + (size_t)l * 64,
                                                 beta + (size_t)l * 64, h, W_out,
                                                 b_out, out, N);
    }
  }
}